// Round 14
// baseline (429.963 us; speedup 1.0000x reference)
//
#include <hip/hip_runtime.h>
#include <hip/hip_bf16.h>

// IO-HMM fwd/bwd chain + projection for MI355X (gfx950).
// L=256 steps, B=128 batch, S=256 states, NL=64 labels.
//
// Kernel 1 (chain): R24 = TWO interleaved chains per block. Ledger
//   R12-R23: the ~745ns barrier-to-barrier interval is INVARIANT to LDS
//   instructions (R20), distinct bytes (R22), per-lane bytes (R23), wave
//   geometry, MFMA depth, prefetch depth, sync mechanism, CU count; only
//   the scatter->coalesced store fix moved it (R18b, -15%). Conclusion:
//   the interval is fixed per-barrier cost (convergence + write->read
//   turnaround + serial latency), not flow. R24 amortizes it: each block
//   advances TWO independent batch-group chains (A: rows bg0..+7, B:
//   bg0+8..+15) per barrier, interleaved in one instruction stream so B's
//   reads/MFMAs fill A's latency shadow. Same direction per block -> T
//   A-frags SHARED (32 regs); bfr regs reused serially A->B; em prefetch
//   depth 1 each. 16 blocks (8 fwd + 8 bwd) x 1024 thr. Writes masked
//   m<8 (BT=8 planes, R22-verified broadcast reads); wave w stores
//   combined row bg0+w (waves 0-7 from A plane, 8-15 from B plane).
//   Arithmetic per chain identical to R18b (absmax 128 expected).
//   If interval ~2x (neutral/chain-step): declare structural ceiling,
//   revert to R18b.
// Kernel 2 (score): R11 version unchanged (gap is timed-region overhead).

typedef _Float16 half8 __attribute__((ext_vector_type(8)));
typedef _Float16 half4 __attribute__((ext_vector_type(4)));
typedef float    f32x4 __attribute__((ext_vector_type(4)));
typedef unsigned long long u64;

#define LL 256
#define BB 128
#define SS 256
#define RSTR8 67  // plane row stride in 8B units (ODD -> conflict-free)
#define RSTRO 65  // score o-plane row stride in 8B units (ODD -> conflict-free)

static __device__ __forceinline__ f32x4 mfma16f(half8 a, half8 b, f32x4 c) {
  return __builtin_amdgcn_mfma_f32_16x16x32_f16(a, b, c, 0, 0, 0);
}

// LDS-only barrier: order ds ops, leave vmcnt (global loads/stores) in flight.
static __device__ __forceinline__ void lds_barrier() {
  __asm__ __volatile__("s_waitcnt lgkmcnt(0)\n\ts_barrier" ::: "memory");
}

// Round-to-nearest-even f16 pack (NOT cvt_pkrtz -- RTZ bias compounds over
// the 255-step chain into ~6% coherent shrink; R8 erratum).
static __device__ __forceinline__ u64 pack4(f32x4 v) {
  union { half4 h; u64 u; } x;
  x.h[0] = (_Float16)v[0];
  x.h[1] = (_Float16)v[1];
  x.h[2] = (_Float16)v[2];
  x.h[3] = (_Float16)v[3];
  return x.u;
}

// 16B logical fragment as two b64 reads (8B-aligned odd-stride layout).
static __device__ __forceinline__ half8 read_frag_s(const u64* plane, int row,
                                                    int kt, int q, int stride8) {
  const int o = row * stride8 + kt * 8 + q * 2;
  union { u64 u[2]; half8 v; } x;
  x.u[0] = plane[o];
  x.u[1] = plane[o + 1];
  return x.v;
}

__global__ __launch_bounds__(1024, 4)
void hmm_chain(const int* __restrict__ sent, const float* __restrict__ emb,
               const float* __restrict__ T, _Float16* __restrict__ fwh,
               _Float16* __restrict__ gh)
{
  __shared__ u64 cA[2][8 * RSTR8];   // chain A carry (batch rows bg0..+7)
  __shared__ u64 cB[2][8 * RSTR8];   // chain B carry (batch rows bg0+8..+15)
  __shared__ u64 vA[2][8 * RSTR8];   // bwd: pack4(v) mirrors
  __shared__ u64 vB[2][8 * RSTR8];
  __shared__ int s_tok[16 * 257];    // [batch row 0..15][l], stride 257

  const int tid  = threadIdx.x;
  const int lane = tid & 63;
  const int w    = tid >> 6;   // wave 0..15 -> states [16w, 16w+16)
  const int m    = lane & 15;  // B col (batch; cols 8-15 junk copies)
  const int mr   = m & 7;      // valid batch row within a chain
  const int q    = lane >> 4;  // quad

  const int  bid = blockIdx.x;
  const bool fwd = (bid < 8);
  const int  bg0 = (fwd ? bid : bid - 8) * 16;   // 16 batch rows per block
  _Float16* const obuf = fwd ? fwh : gh;
  const int  st  = 16 * w + 4 * q;   // this lane's first state

  // ---- stage sentence tokens (16 rows) ----
  for (int idx = tid; idx < 16 * LL; idx += 1024) {
    int bb = idx >> 8, l2 = idx & 255;
    s_tok[bb * 257 + l2] = sent[(bg0 + bb) * LL + l2];
  }
  __syncthreads();

  // ---- load T fragments (A operand), SHARED by both chains: 32 regs
  half8 a_hi[8];
#pragma unroll
  for (int kt = 0; kt < 8; ++kt) {
    const int r0 = 16 * w + m;           // state (M index)
    const int kb = 32 * kt + 8 * q;      // k base
    float v[8];
    if (fwd) {
      f32x4 f0 = *(const f32x4*)(T + r0 * 256 + kb);
      f32x4 f1 = *(const f32x4*)(T + r0 * 256 + kb + 4);
#pragma unroll
      for (int j = 0; j < 4; ++j) { v[j] = f0[j]; v[4 + j] = f1[j]; }
    } else {
#pragma unroll
      for (int j = 0; j < 8; ++j) v[j] = T[(kb + j) * 256 + r0]; // T^T
    }
    half8 hi;
#pragma unroll
    for (int j = 0; j < 8; ++j) hi[j] = (_Float16)v[j];   // RNE
    a_hi[kt] = hi;
  }

  // ---- init carries at l0; bwd also inits v planes = 1 ----
  const int l0 = fwd ? 0 : (LL - 1);
  {
    const int tkA = s_tok[mr * 257 + l0];
    const int tkB = s_tok[(8 + mr) * 257 + l0];
    f32x4 eA = *(const f32x4*)(emb + (size_t)tkA * 256 + st);
    f32x4 eB = *(const f32x4*)(emb + (size_t)tkB * 256 + st);
    if (m < 8) {
      cA[0][m * RSTR8 + 4 * w + q] = pack4(eA);
      cB[0][m * RSTR8 + 4 * w + q] = pack4(eB);
      if (!fwd) {
        f32x4 one = 1.0f;
        u64 pone = pack4(one);
        vA[0][m * RSTR8 + 4 * w + q] = pone;   // g[L-1] = 1
        vB[0][m * RSTR8 + 4 * w + q] = pone;
      }
    }
  }

  // ---- prefetch em for step 1 (both chains) ----
  f32x4 em_prefA, em_prefB;
  {
    const int l1 = fwd ? 1 : (LL - 2);
    em_prefA = *(const f32x4*)(emb + (size_t)s_tok[mr * 257 + l1] * 256 + st);
    em_prefB = *(const f32x4*)(emb + (size_t)s_tok[(8 + mr) * 257 + l1] * 256 + st);
  }
  __syncthreads();

  // ---- main chain: each barrier interval advances BOTH chains one step.
  for (int s = 1; s < LL; ++s) {
    const int lp = fwd ? (s - 1) : (LL - s);   // prev step's l
    const int rb = (s - 1) & 1, wb = s & 1;

    // deferred out-row read for step s-1: wave w handles combined row bg0+w
    // (waves 0-7 from chain-A plane, 8-15 from chain-B plane).
    u64 ovv;
    {
      const u64* opA = fwd ? &cA[rb][0] : &vA[rb][0];
      const u64* opB = fwd ? &cB[rb][0] : &vB[rb][0];
      ovv = (w < 8) ? opA[w * RSTR8 + lane] : opB[(w - 8) * RSTR8 + lane];
    }

    // consume prefetched em; issue next prefetch (tokens from LDS)
    f32x4 emA = em_prefA, emB = em_prefB;
    {
      const int ln = fwd ? (s + 1 < LL ? s + 1 : LL - 1)
                         : ((LL - 2) - s > 0 ? (LL - 2) - s : 0);
      em_prefA = *(const f32x4*)(emb + (size_t)s_tok[mr * 257 + ln] * 256 + st);
      em_prefB = *(const f32x4*)(emb + (size_t)s_tok[(8 + mr) * 257 + ln] * 256 + st);
    }

    // ---- chain A: read frags (broadcast rows 0-7), 8 MFMA, write ----
    {
      const u64* pr = &cA[rb][0];
      half8 bfr[8];
#pragma unroll
      for (int kt = 0; kt < 8; ++kt)
        bfr[kt] = read_frag_s(pr, mr, kt, q, RSTR8);
      f32x4 hh = 0.0f;
#pragma unroll
      for (int kt = 0; kt < 8; ++kt)
        hh = mfma16f(a_hi[kt], bfr[kt], hh);
      f32x4 cn = hh * emA;
      if (m < 8) {
        cA[wb][m * RSTR8 + 4 * w + q] = pack4(cn);
        if (!fwd) vA[wb][m * RSTR8 + 4 * w + q] = pack4(hh);
      }
    }

    // ---- chain B: same, reusing bfr registers ----
    {
      const u64* pr = &cB[rb][0];
      half8 bfr[8];
#pragma unroll
      for (int kt = 0; kt < 8; ++kt)
        bfr[kt] = read_frag_s(pr, mr, kt, q, RSTR8);
      f32x4 hh = 0.0f;
#pragma unroll
      for (int kt = 0; kt < 8; ++kt)
        hh = mfma16f(a_hi[kt], bfr[kt], hh);
      f32x4 cn = hh * emB;
      if (m < 8) {
        cB[wb][m * RSTR8 + 4 * w + q] = pack4(cn);
        if (!fwd) vB[wb][m * RSTR8 + 4 * w + q] = pack4(hh);
      }
    }

    lds_barrier();  // LDS ordering only; global stores/loads stay in flight
    // coalesced 512B store of step s-1's combined row (post-barrier)
    *(u64*)(obuf + ((size_t)lp * BB + bg0 + w) * SS + lane * 4) = ovv;
  }

  // ---- epilogue: store the final step's rows (plane 1 = step 255) ----
  {
    const int lp = fwd ? (LL - 1) : 0;
    const u64* opA = fwd ? &cA[1][0] : &vA[1][0];
    const u64* opB = fwd ? &cB[1][0] : &vB[1][0];
    u64 ovv = (w < 8) ? opA[w * RSTR8 + lane] : opB[(w - 8) * RSTR8 + lane];
    *(u64*)(obuf + ((size_t)lp * BB + bg0 + w) * SS + lane * 4) = ovv;
  }
}

__global__ __launch_bounds__(256, 2)
void hmm_score(const _Float16* __restrict__ fwh, const _Float16* __restrict__ gh,
               const float* __restrict__ outm, float* __restrict__ score)
{
  __shared__ u64 p_pl[64 * RSTR8];   // p = fw*g, [row][k] f16
  __shared__ u64 o_pl[64 * RSTRO];   // outm^T,   [n][k]  f16

  const int tid  = threadIdx.x;
  const int lane = tid & 63;
  const int w    = tid >> 6;
  const int rh   = w >> 1;     // row half: rows [32rh, 32rh+32)
  const int np   = w & 1;      // n-pair: n-tiles {2np, 2np+1}
  const int m    = lane & 15;
  const int q    = lane >> 4;
  const int R0   = blockIdx.x * 64;  // row = l*128 + b

  // ---- stage outm -> o_pl[n][k] f16 (RNE, hi only), coalesced f32x4 loads
  {
    _Float16* o_h = (_Float16*)o_pl;
    for (int i = tid; i < 4096; i += 256) {
      f32x4 v = *(const f32x4*)(outm + i * 4);   // flat = k*64+n
      int k = i >> 4, n0 = (i & 15) * 4;
#pragma unroll
      for (int r = 0; r < 4; ++r)
        o_h[(n0 + r) * (RSTRO * 4) + k] = (_Float16)v[r];
    }
  }

  // ---- stage p = fw * g (f16 packed mul, RNE) ----
  for (int idx = tid; idx < 64 * 64; idx += 256) {
    int row = idx >> 6, c = idx & 63;       // c = 8B column index
    union { u64 u; half4 h; } a, b, p;
    a.u = *(const u64*)(fwh + (size_t)(R0 + row) * 256 + c * 4);
    b.u = *(const u64*)(gh  + (size_t)(R0 + row) * 256 + c * 4);
    p.h = a.h * b.h;                        // v_pk_mul_f16 x2
    p_pl[row * RSTR8 + c] = p.u;
  }
  lds_barrier();

  f32x4 acc[2][2];
#pragma unroll
  for (int j = 0; j < 2; ++j)
#pragma unroll
    for (int jn = 0; jn < 2; ++jn) acc[j][jn] = 0.0f;

#pragma unroll
  for (int kt = 0; kt < 8; ++kt) {
    half8 of[2];
#pragma unroll
    for (int jn = 0; jn < 2; ++jn)
      of[jn] = read_frag_s(o_pl, 16 * (2 * np + jn) + m, kt, q, RSTRO);
#pragma unroll
    for (int j = 0; j < 2; ++j) {
      half8 pf = read_frag_s(p_pl, 32 * rh + 16 * j + m, kt, q, RSTR8);
#pragma unroll
      for (int jn = 0; jn < 2; ++jn)
        acc[j][jn] = mfma16f(pf, of[jn], acc[j][jn]);
    }
  }

#pragma unroll
  for (int j = 0; j < 2; ++j) {
#pragma unroll
    for (int jn = 0; jn < 2; ++jn) {
#pragma unroll
      for (int r = 0; r < 4; ++r) {
        int row = R0 + 32 * rh + 16 * j + 4 * q + r;
        int l = row >> 7, b = row & 127;
        score[(size_t)b * 16384 + l * 64 + 16 * (2 * np + jn) + m] = acc[j][jn][r];
      }
    }
  }
}

extern "C" void kernel_launch(void* const* d_in, const int* in_sizes, int n_in,
                              void* d_out, int out_size, void* d_ws, size_t ws_size,
                              hipStream_t stream) {
  (void)in_sizes; (void)n_in; (void)out_size; (void)ws_size;
  const int*   sent = (const int*)d_in[0];
  const float* emb  = (const float*)d_in[1];
  const float* T    = (const float*)d_in[2];
  const float* outm = (const float*)d_in[3];
  _Float16* fwh = (_Float16*)d_ws;                  // [L][B][S] f16, 16 MB
  _Float16* gh  = fwh + (size_t)LL * BB * SS;       // [L][B][S] f16, 16 MB

  hmm_chain<<<16, 1024, 0, stream>>>(sent, emb, T, fwh, gh);
  hmm_score<<<512, 256, 0, stream>>>(fwh, gh, outm, (float*)d_out);
}

// Round 15
// 264.292 us; speedup vs baseline: 1.6268x; 1.6268x over previous
//
#include <hip/hip_runtime.h>
#include <hip/hip_bf16.h>

// IO-HMM fwd/bwd chain + projection for MI355X (gfx950).
// L=256 steps, B=128 batch, S=256 states, NL=64 labels.
//
// FINAL (R25) = R18b, the session best (262.1us total; chain ~183us).
// Structure: 16 blocks (8 fwd + 8 bwd) x 1024 threads; 16 waves x 1 M-tile
// (wave owns 16 states); T as single f16 A-frags in regs; carry = f16 LDS
// plane, double-buffered, odd stride 67 (0 conflicts); em prefetch depth 1;
// RNE packs only; lds-only barrier; COALESCED DEFERRED output stores (wave
// w stores batch-row w of step s-1 as ONE lane-linear 512B store -- the
// R18b win: scatter-store retire tail ~280cyc/step removed, -15%).
//
// Closed ledger (R12-R24): step interval ~718ns is INVARIANT to LDS
// instruction count (R20), distinct bytes (R22), per-lane bytes/requests
// (R23), wave geometry (16x1 best: R19/R21), MFMA chain depth/pipelining
// (R15/R16), em prefetch depth (R15), sync mechanism (R17b flags: worse),
// and scales ~linearly with per-interval work (R24: 2x work -> 1.83x).
// All throughput pipes <10% utilized. Conclusion: latency-bound serial
// recurrence -- 255 dependent steps x (write -> barrier -> read-latency ->
// 8-dep-MFMA -> pack) ~ 700-750ns structural floor. The parallel
// matrix-scan escape is dead: M_s = diag(e_s)T is per-batch-element
// (token-dependent), so prefix products cost 128x the matrix FLOPs.
// Floor: 255 x ~718ns = 183us chain + ~35us score + ~45us launch/timed
// overhead = ~262us.
//
// Kernel 2 (score): R11 version (outm staged once to LDS [n][k] f16, odd
// stride 65; p = fw*g via v_pk_mul_f16; 32 MFMA/wave). Seven variants
// R3-R11 showed the chain<->total gap is timed-region overhead.

typedef _Float16 half8 __attribute__((ext_vector_type(8)));
typedef _Float16 half4 __attribute__((ext_vector_type(4)));
typedef float    f32x4 __attribute__((ext_vector_type(4)));
typedef unsigned long long u64;

#define LL 256
#define BB 128
#define SS 256
#define BT 16
#define RSTR8 67   // carry/p-plane row stride in 8B units (ODD -> conflict-free)
#define RSTRO 65   // o-plane row stride in 8B units (ODD -> conflict-free)

static __device__ __forceinline__ f32x4 mfma16f(half8 a, half8 b, f32x4 c) {
  return __builtin_amdgcn_mfma_f32_16x16x32_f16(a, b, c, 0, 0, 0);
}

// LDS-only barrier: order ds ops, leave vmcnt (global loads/stores) in flight.
static __device__ __forceinline__ void lds_barrier() {
  __asm__ __volatile__("s_waitcnt lgkmcnt(0)\n\ts_barrier" ::: "memory");
}

// Round-to-nearest-even f16 pack (NOT cvt_pkrtz -- RTZ bias compounds over
// the 255-step chain into ~6% coherent shrink; R8 erratum).
static __device__ __forceinline__ u64 pack4(f32x4 v) {
  union { half4 h; u64 u; } x;
  x.h[0] = (_Float16)v[0];
  x.h[1] = (_Float16)v[1];
  x.h[2] = (_Float16)v[2];
  x.h[3] = (_Float16)v[3];
  return x.u;
}

// 16B logical fragment as two b64 reads (8B-aligned odd-stride layout).
static __device__ __forceinline__ half8 read_frag_s(const u64* plane, int row,
                                                    int kt, int q, int stride8) {
  const int o = row * stride8 + kt * 8 + q * 2;
  union { u64 u[2]; half8 v; } x;
  x.u[0] = plane[o];
  x.u[1] = plane[o + 1];
  return x.v;
}

__global__ __launch_bounds__(1024, 4)
void hmm_chain(const int* __restrict__ sent, const float* __restrict__ emb,
               const float* __restrict__ T, _Float16* __restrict__ fwh,
               _Float16* __restrict__ gh)
{
  __shared__ u64 s_carry[2][BT * RSTR8]; // [buf][row*stride], single f16 plane
  __shared__ u64 v_pl[2][BT * RSTR8];    // bwd: pack4(v) mirror plane, dbuf
  __shared__ int s_tok[BT * 257];        // [batch][l], stride 257

  const int tid  = threadIdx.x;
  const int lane = tid & 63;
  const int w    = tid >> 6;   // wave 0..15 -> states [16w, 16w+16)
  const int m    = lane & 15;  // A row-in-tile / B col (= batch)
  const int q    = lane >> 4;  // quad

  const int  bid = blockIdx.x;
  const bool fwd = (bid < 8);
  const int  bg0 = (fwd ? bid : bid - 8) * BT;
  _Float16* const obuf = fwd ? fwh : gh;
  const int  st  = 16 * w + 4 * q;       // this lane's first state

  // ---- stage sentence tokens ----
  for (int idx = tid; idx < BT * LL; idx += 1024) {
    int bb = idx >> 8, l2 = idx & 255;
    s_tok[bb * 257 + l2] = sent[(bg0 + bb) * LL + l2];
  }
  __syncthreads();

  // ---- load T fragments (A operand), single f16: 8 frags = 32 regs
  half8 a_hi[8];
#pragma unroll
  for (int kt = 0; kt < 8; ++kt) {
    const int r0 = 16 * w + m;           // state (M index)
    const int kb = 32 * kt + 8 * q;      // k base
    float v[8];
    if (fwd) {
      f32x4 f0 = *(const f32x4*)(T + r0 * 256 + kb);
      f32x4 f1 = *(const f32x4*)(T + r0 * 256 + kb + 4);
#pragma unroll
      for (int j = 0; j < 4; ++j) { v[j] = f0[j]; v[4 + j] = f1[j]; }
    } else {
#pragma unroll
      for (int j = 0; j < 8; ++j) v[j] = T[(kb + j) * 256 + r0]; // T^T
    }
    half8 hi;
#pragma unroll
    for (int j = 0; j < 8; ++j) hi[j] = (_Float16)v[j];   // RNE
    a_hi[kt] = hi;
  }

  // ---- init carry at l0; bwd also inits v_pl[0] = 1 (step-0 output g[l0])
  const int l0 = fwd ? 0 : (LL - 1);
  {
    const int tok0 = s_tok[m * 257 + l0];
    f32x4 e0 = *(const f32x4*)(emb + (size_t)tok0 * 256 + st);
    u64 pc = pack4(e0);                       // carry = em[l0] both dirs
    s_carry[0][m * RSTR8 + 4 * w + q] = pc;
    if (!fwd) {
      f32x4 one = 1.0f;
      v_pl[0][m * RSTR8 + 4 * w + q] = pack4(one);  // g[L-1] = 1
    }
  }

  // ---- prefetch em for step 1 ----
  f32x4 em_pref;
  {
    const int l1 = fwd ? 1 : (LL - 2);
    const int tok1 = s_tok[m * 257 + l1];
    em_pref = *(const f32x4*)(emb + (size_t)tok1 * 256 + st);
  }
  __syncthreads();

  // ---- main chain ----
  // Step s stores step s-1's output COALESCED: wave w reads batch-row w of
  // the s-1 output plane (fwd: carry; bwd: v_pl) lane-linear and issues ONE
  // 512B store (8 full lines).
  for (int s = 1; s < LL; ++s) {
    const int lp = fwd ? (s - 1) : (LL - s);   // prev step's l
    const int rb = (s - 1) & 1, wb = s & 1;

    const u64* pr = &s_carry[rb][0];
    half8 bfr[8];
#pragma unroll
    for (int kt = 0; kt < 8; ++kt)
      bfr[kt] = read_frag_s(pr, m, kt, q, RSTR8);

    // deferred out-row read for step s-1 (coalesced store issued below)
    const u64* op = fwd ? &s_carry[rb][0] : &v_pl[rb][0];
    u64 ov = op[w * RSTR8 + lane];

    // consume prefetched em; issue next prefetch (token from LDS)
    f32x4 em_now = em_pref;
    {
      const int ln = fwd ? (s + 1 < LL ? s + 1 : LL - 1)
                         : ((LL - 2) - s > 0 ? (LL - 2) - s : 0);
      const int tokn = s_tok[m * 257 + ln];
      em_pref = *(const f32x4*)(emb + (size_t)tokn * 256 + st);
    }

    // single-product f16 matmul (8 MFMA/wave/step)
    f32x4 hh = 0.0f;
#pragma unroll
    for (int kt = 0; kt < 8; ++kt)
      hh = mfma16f(a_hi[kt], bfr[kt], hh);
    f32x4 v  = hh;                     // pre-em matmul result
    f32x4 cn = v * em_now;             // new carry

    u64 p0 = pack4(cn);
    s_carry[wb][m * RSTR8 + 4 * w + q] = p0;
    if (!fwd)
      v_pl[wb][m * RSTR8 + 4 * w + q] = pack4(v);  // g[l] = v (bit-identical)

    // coalesced 512B store of the previous step's row (8 full lines)
    *(u64*)(obuf + ((size_t)lp * BB + bg0 + w) * SS + lane * 4) = ov;

    lds_barrier();  // LDS ordering only; global stores/loads stay in flight
  }

  // ---- epilogue: store the final step's row (plane 1 = step 255) ----
  {
    const int lp = fwd ? (LL - 1) : 0;
    const u64* op = fwd ? &s_carry[1][0] : &v_pl[1][0];
    u64 ov = op[w * RSTR8 + lane];
    *(u64*)(obuf + ((size_t)lp * BB + bg0 + w) * SS + lane * 4) = ov;
  }
}

__global__ __launch_bounds__(256, 2)
void hmm_score(const _Float16* __restrict__ fwh, const _Float16* __restrict__ gh,
               const float* __restrict__ outm, float* __restrict__ score)
{
  __shared__ u64 p_pl[64 * RSTR8];   // p = fw*g, [row][k] f16
  __shared__ u64 o_pl[64 * RSTRO];   // outm^T,   [n][k]  f16

  const int tid  = threadIdx.x;
  const int lane = tid & 63;
  const int w    = tid >> 6;
  const int rh   = w >> 1;     // row half: rows [32rh, 32rh+32)
  const int np   = w & 1;      // n-pair: n-tiles {2np, 2np+1}
  const int m    = lane & 15;
  const int q    = lane >> 4;
  const int R0   = blockIdx.x * 64;  // row = l*128 + b

  // ---- stage outm -> o_pl[n][k] f16 (RNE, hi only), coalesced f32x4 loads
  {
    _Float16* o_h = (_Float16*)o_pl;
    for (int i = tid; i < 4096; i += 256) {
      f32x4 v = *(const f32x4*)(outm + i * 4);   // flat = k*64+n
      int k = i >> 4, n0 = (i & 15) * 4;
#pragma unroll
      for (int r = 0; r < 4; ++r)
        o_h[(n0 + r) * (RSTRO * 4) + k] = (_Float16)v[r];
    }
  }

  // ---- stage p = fw * g (f16 packed mul, RNE) ----
  for (int idx = tid; idx < 64 * 64; idx += 256) {
    int row = idx >> 6, c = idx & 63;       // c = 8B column index
    union { u64 u; half4 h; } a, b, p;
    a.u = *(const u64*)(fwh + (size_t)(R0 + row) * 256 + c * 4);
    b.u = *(const u64*)(gh  + (size_t)(R0 + row) * 256 + c * 4);
    p.h = a.h * b.h;                        // v_pk_mul_f16 x2
    p_pl[row * RSTR8 + c] = p.u;
  }
  lds_barrier();

  f32x4 acc[2][2];
#pragma unroll
  for (int j = 0; j < 2; ++j)
#pragma unroll
    for (int jn = 0; jn < 2; ++jn) acc[j][jn] = 0.0f;

#pragma unroll
  for (int kt = 0; kt < 8; ++kt) {
    half8 of[2];
#pragma unroll
    for (int jn = 0; jn < 2; ++jn)
      of[jn] = read_frag_s(o_pl, 16 * (2 * np + jn) + m, kt, q, RSTRO);
#pragma unroll
    for (int j = 0; j < 2; ++j) {
      half8 pf = read_frag_s(p_pl, 32 * rh + 16 * j + m, kt, q, RSTR8);
#pragma unroll
      for (int jn = 0; jn < 2; ++jn)
        acc[j][jn] = mfma16f(pf, of[jn], acc[j][jn]);
    }
  }

#pragma unroll
  for (int j = 0; j < 2; ++j) {
#pragma unroll
    for (int jn = 0; jn < 2; ++jn) {
#pragma unroll
      for (int r = 0; r < 4; ++r) {
        int row = R0 + 32 * rh + 16 * j + 4 * q + r;
        int l = row >> 7, b = row & 127;
        score[(size_t)b * 16384 + l * 64 + 16 * (2 * np + jn) + m] = acc[j][jn][r];
      }
    }
  }
}

extern "C" void kernel_launch(void* const* d_in, const int* in_sizes, int n_in,
                              void* d_out, int out_size, void* d_ws, size_t ws_size,
                              hipStream_t stream) {
  (void)in_sizes; (void)n_in; (void)out_size; (void)ws_size;
  const int*   sent = (const int*)d_in[0];
  const float* emb  = (const float*)d_in[1];
  const float* T    = (const float*)d_in[2];
  const float* outm = (const float*)d_in[3];
  _Float16* fwh = (_Float16*)d_ws;                  // [L][B][S] f16, 16 MB
  _Float16* gh  = fwh + (size_t)LL * BB * SS;       // [L][B][S] f16, 16 MB

  hmm_chain<<<16, 1024, 0, stream>>>(sent, emb, T, fwh, gh);
  hmm_score<<<512, 256, 0, stream>>>(fwh, gh, outm, (float*)d_out);
}